// Round 2
// baseline (427.719 us; speedup 1.0000x reference)
//
#include <hip/hip_runtime.h>

// C51 categorical projection. BS = 524288 rows x 51 atoms, fp32.
// Round 2: LDS-issue-bound fix. Scatter now uses atomicAdd on LDS
// (single ds_add_f32, no return) instead of += (ds_read+ds_write RMW pair):
// halves scatter LDS instructions and kills the serial RMW chain.
// 128-thread blocks: 26112 B LDS -> 6 blocks/CU (12 waves/CU), finer
// barriers, 4096 blocks.
//
// Per-atom math simplified: b = clamp(fma(c, a, base2), 0, 50) where
// base2 = 2.5r + 25 - 25c, c = 0.99*not_done. ui = min(li+1, 50) with
// wl = (1 - wu) reproduces the reference's l==u special case exactly
// (integer b -> wu = 0 -> full mass at li, zero at ui).

#define NUM_ATOMS 51
#define ROWS_PER_BLOCK 128
#define TILE_ELEMS (ROWS_PER_BLOCK * NUM_ATOMS)   // 6528 floats = 26112 B
#define VEC4_ITERS 12                             // 12*128 float4 = 6144 elems
#define REM_ITERS 3                               // 3*128 = 384 remainder elems

__global__ __launch_bounds__(ROWS_PER_BLOCK, 3) void catproj_kernel(
    const float* __restrict__ reward,
    const float* __restrict__ probs,
    const float* __restrict__ not_done,
    float* __restrict__ out)
{
    __shared__ float lds[TILE_ELEMS];

    const int tid = threadIdx.x;
    const int row = blockIdx.x * ROWS_PER_BLOCK + tid;
    const int base = blockIdx.x * TILE_ELEMS;

    const float r  = reward[row];
    const float nd = not_done[row];

    // ---- Stage probs tile into LDS: flat coalesced float4 copy ----
    const float4* __restrict__ p4 = (const float4*)(probs + base);
    float4* __restrict__ l4 = (float4*)lds;
#pragma unroll
    for (int k = 0; k < VEC4_ITERS; ++k) {
        const int i4 = k * ROWS_PER_BLOCK + tid;
        l4[i4] = p4[i4];
    }
#pragma unroll
    for (int k = 0; k < REM_ITERS; ++k) {
        const int g = VEC4_ITERS * ROWS_PER_BLOCK * 4 + k * ROWS_PER_BLOCK + tid;
        lds[g] = probs[base + g];
    }
    __syncthreads();

    // ---- Read own row into registers (static indices -> VGPRs) ----
    // Row base tid*51 words -> bank (19*tid) mod 32: all 32 banks covered,
    // 2 lanes/bank (free aliasing).
    float* __restrict__ myrow = lds + tid * NUM_ATOMS;
    float p[NUM_ATOMS];
#pragma unroll
    for (int a = 0; a < NUM_ATOMS; ++a) p[a] = myrow[a];

    // Own row is exclusively this thread's from here (no barrier needed)
#pragma unroll
    for (int a = 0; a < NUM_ATOMS; ++a) myrow[a] = 0.0f;

    // ---- Projection scatter: one ds_add_f32 per contribution ----
    const float c     = 0.99f * nd;
    const float base2 = fmaf(-25.0f, c, fmaf(2.5f, r, 25.0f)); // 2.5r+25-25c
#pragma unroll
    for (int a = 0; a < NUM_ATOMS; ++a) {
        float b = fmaf(c, (float)a, base2);          // == (clip(nav)+10)*2.5
        b = fminf(fmaxf(b, 0.0f), 50.0f);
        const float lf = floorf(b);
        const int   li = (int)lf;
        const int   ui = min(li + 1, NUM_ATOMS - 1);
        const float pa = p[a];
        const float mu = (b - lf) * pa;              // upper mass
        const float ml = pa - mu;                    // lower mass = (1-wu)*pa
        atomicAdd(&myrow[li], ml);                   // ds_add_f32 (no return)
        atomicAdd(&myrow[ui], mu);
    }
    __syncthreads();

    // ---- Flat coalesced writeout ----
    float4* __restrict__ o4 = (float4*)(out + base);
#pragma unroll
    for (int k = 0; k < VEC4_ITERS; ++k) {
        const int i4 = k * ROWS_PER_BLOCK + tid;
        o4[i4] = l4[i4];
    }
#pragma unroll
    for (int k = 0; k < REM_ITERS; ++k) {
        const int g = VEC4_ITERS * ROWS_PER_BLOCK * 4 + k * ROWS_PER_BLOCK + tid;
        out[base + g] = lds[g];
    }
}

extern "C" void kernel_launch(void* const* d_in, const int* in_sizes, int n_in,
                              void* d_out, int out_size, void* d_ws, size_t ws_size,
                              hipStream_t stream) {
    const float* reward   = (const float*)d_in[0];
    const float* probs    = (const float*)d_in[1];
    const float* not_done = (const float*)d_in[2];
    float* out = (float*)d_out;

    const int bs = in_sizes[0];                   // 524288
    const int grid = bs / ROWS_PER_BLOCK;         // 4096 blocks
    catproj_kernel<<<grid, ROWS_PER_BLOCK, 0, stream>>>(reward, probs, not_done, out);
}

// Round 3
// 314.802 us; speedup vs baseline: 1.3587x; 1.3587x over previous
//
#include <hip/hip_runtime.h>

// C51 categorical projection. BS = 524288 rows x 51 atoms, fp32.
// Round 3: merge-scatter. b(a) = clamp(base2 + c*a, 0, 50) is monotone in a
// with slope c <= 0.99 < 1, so li(a) = floor(b) advances by 0 or 1 per atom.
// Keep accL (mass for bin cur) and accU (carry for cur+1) in registers and
// emit one predicated LDS write per bin: <=53 LDS writes, ZERO reads, no
// RMW dependency chain (round 1: 102r+102w scatter; round 2's ds_add_f32
// atomics were 4x slower -- never again).
//
// p-row read directly from global (wave spans a contiguous 13KB -> L1 reuse).
// Tile zeroed collectively with flat b128 (15 issues). Writeout is a flat
// coalesced b128 copy. ~83 LDS issues/thread vs round 1's ~336.

#define NUM_ATOMS 51
#define RPB 256
#define TILE (RPB * NUM_ATOMS)      // 13056 floats = 52224 B -> 3 blocks/CU

__global__ __launch_bounds__(RPB, 3) void catproj_kernel(
    const float* __restrict__ reward,
    const float* __restrict__ probs,
    const float* __restrict__ not_done,
    float* __restrict__ out)
{
    __shared__ float lds[TILE];

    const int tid = threadIdx.x;
    const int row = blockIdx.x * RPB + tid;
    const int base = blockIdx.x * TILE;

    const float r  = reward[row];
    const float nd = not_done[row];

    // ---- Collective zero of the whole tile (flat, conflict-free b128) ----
    float4* __restrict__ l4 = (float4*)lds;
    const float4 z4 = {0.f, 0.f, 0.f, 0.f};
#pragma unroll
    for (int k = 0; k < 12; ++k) l4[k * RPB + tid] = z4;
#pragma unroll
    for (int k = 0; k < 3; ++k) lds[12 * RPB * 4 + k * RPB + tid] = 0.f;
    __syncthreads();   // other threads zero my row; must finish before scatter

    // ---- Merge-scatter: one write per output bin, no reads ----
    const float c     = 0.99f * nd;
    const float base2 = fmaf(-25.f, c, fmaf(2.5f, r, 25.f)); // 2.5r+25-25c
    const float* __restrict__ prow  = probs + row * NUM_ATOMS;
    float* __restrict__       myrow = lds + tid * NUM_ATOMS;

    float accL = 0.f, accU = 0.f;
    // cur = li(0); loop's a=0 iteration then accumulates without advancing.
    int cur = (int)floorf(fminf(fmaxf(base2, 0.f), 50.f));
#pragma unroll
    for (int a = 0; a < NUM_ATOMS; ++a) {
        float b = fmaf(c, (float)a, base2);
        b = fminf(fmaxf(b, 0.f), 50.f);
        const float lf = floorf(b);
        const int   li = (int)lf;
        const float pa = prow[a];
        const float mu = (b - lf) * pa;   // upper mass (0 when b integral)
        const float ml = pa - mu;         // lower mass
        if (li != cur) {                  // advances by exactly 1 (slope < 1)
            myrow[cur] = accL;            // bin cur is complete: single write
            accL = accU;
            accU = 0.f;
            cur  = li;
        }
        accL += ml;
        accU += mu;
    }
    myrow[cur] = accL;
    if (cur < NUM_ATOMS - 1) myrow[cur + 1] = accU;  // accU==0 when cur==50
    __syncthreads();

    // ---- Flat coalesced writeout ----
    const float4* __restrict__ s4 = (const float4*)lds;
    float4* __restrict__ o4 = (float4*)(out + base);
#pragma unroll
    for (int k = 0; k < 12; ++k) o4[k * RPB + tid] = s4[k * RPB + tid];
#pragma unroll
    for (int k = 0; k < 3; ++k) {
        const int g = 12 * RPB * 4 + k * RPB + tid;
        out[base + g] = lds[g];
    }
}

extern "C" void kernel_launch(void* const* d_in, const int* in_sizes, int n_in,
                              void* d_out, int out_size, void* d_ws, size_t ws_size,
                              hipStream_t stream) {
    const float* reward   = (const float*)d_in[0];
    const float* probs    = (const float*)d_in[1];
    const float* not_done = (const float*)d_in[2];
    float* out = (float*)d_out;

    const int bs = in_sizes[0];              // 524288
    const int grid = bs / RPB;               // 2048 blocks
    catproj_kernel<<<grid, RPB, 0, stream>>>(reward, probs, not_done, out);
}

// Round 4
// 198.326 us; speedup vs baseline: 2.1567x; 1.5873x over previous
//
#include <hip/hip_runtime.h>

// C51 categorical projection. BS = 524288 rows x 51 atoms, fp32.
// Round 4 = round 1's coalesced read path + round 3's merge-scatter.
//
// History: R1 (stage + 102r/102w RMW scatter) = 71 us, LDS-issue-bound.
// R2 (ds_add_f32 atomics) = 298 us -- LDS atomics ~5x slower, never again.
// R3 (merge-scatter but direct global row reads) = 184 us -- 204B-stride
// scalar loads fragment into ~64 lines/wave-load, FETCH 54->165 MB.
//
// This round: stage probs tile into LDS with flat coalesced b128 copy
// (FETCH stays ~54 MB); read own contiguous row to registers (ds_read2);
// zero own row (ds_write2); merge-scatter: b(a) = clamp(base2 + c*a, 0, 50)
// is monotone with slope c <= 0.99 < 1 so li advances by 0 or 1 -> each
// output bin written EXACTLY once, <=53 predicated ds_write_b32, zero LDS
// reads, no RMW chain. Two barriers total.

#define NUM_ATOMS 51
#define RPB 256
#define TILE (RPB * NUM_ATOMS)      // 13056 floats = 52224 B -> 3 blocks/CU

__global__ __launch_bounds__(RPB, 3) void catproj_kernel(
    const float* __restrict__ reward,
    const float* __restrict__ probs,
    const float* __restrict__ not_done,
    float* __restrict__ out)
{
    __shared__ float lds[TILE];

    const int tid = threadIdx.x;
    const int row = blockIdx.x * RPB + tid;
    const int base = blockIdx.x * TILE;

    const float r  = reward[row];
    const float nd = not_done[row];

    // ---- Stage probs tile into LDS: flat coalesced b128 copy ----
    const float4* __restrict__ p4 = (const float4*)(probs + base);
    float4* __restrict__ l4 = (float4*)lds;
#pragma unroll
    for (int k = 0; k < 12; ++k) {
        const int i4 = k * RPB + tid;
        l4[i4] = p4[i4];
    }
#pragma unroll
    for (int k = 0; k < 3; ++k) {
        const int g = 12 * RPB * 4 + k * RPB + tid;
        lds[g] = probs[base + g];
    }
    __syncthreads();

    // ---- Read own contiguous row into registers ----
    // Row base tid*51 words: bank (19*tid) mod 32, gcd(19,32)=1 -> full
    // bank spread. Consecutive addrs -> compiler emits ds_read2_b32.
    float* __restrict__ myrow = lds + tid * NUM_ATOMS;
    float p[NUM_ATOMS];
#pragma unroll
    for (int a = 0; a < NUM_ATOMS; ++a) p[a] = myrow[a];

    // Own row only from here on -> no barrier until writeout.
#pragma unroll
    for (int a = 0; a < NUM_ATOMS; ++a) myrow[a] = 0.0f;

    // ---- Merge-scatter: one write per output bin, no reads ----
    const float c     = 0.99f * nd;
    const float base2 = fmaf(-25.f, c, fmaf(2.5f, r, 25.f)); // 2.5r+25-25c
    float accL = 0.f, accU = 0.f;
    int cur = (int)floorf(fminf(fmaxf(base2, 0.f), 50.f));   // li(0)
#pragma unroll
    for (int a = 0; a < NUM_ATOMS; ++a) {
        float b = fmaf(c, (float)a, base2);
        b = fminf(fmaxf(b, 0.f), 50.f);
        const float lf = floorf(b);
        const int   li = (int)lf;
        const float pa = p[a];
        const float mu = (b - lf) * pa;   // upper mass (0 when b integral)
        const float ml = pa - mu;         // lower mass
        if (li != cur) {                  // advances by exactly 1 (slope < 1)
            myrow[cur] = accL;            // bin complete: single write
            accL = accU;
            accU = 0.f;
            cur  = li;
        }
        accL += ml;
        accU += mu;
    }
    myrow[cur] = accL;
    if (cur < NUM_ATOMS - 1) myrow[cur + 1] = accU;  // accU==0 when cur==50
    __syncthreads();

    // ---- Flat coalesced writeout ----
    const float4* __restrict__ s4 = (const float4*)lds;
    float4* __restrict__ o4 = (float4*)(out + base);
#pragma unroll
    for (int k = 0; k < 12; ++k) {
        const int i4 = k * RPB + tid;
        o4[i4] = s4[i4];
    }
#pragma unroll
    for (int k = 0; k < 3; ++k) {
        const int g = 12 * RPB * 4 + k * RPB + tid;
        out[base + g] = lds[g];
    }
}

extern "C" void kernel_launch(void* const* d_in, const int* in_sizes, int n_in,
                              void* d_out, int out_size, void* d_ws, size_t ws_size,
                              hipStream_t stream) {
    const float* reward   = (const float*)d_in[0];
    const float* probs    = (const float*)d_in[1];
    const float* not_done = (const float*)d_in[2];
    float* out = (float*)d_out;

    const int bs = in_sizes[0];              // 524288
    const int grid = bs / RPB;               // 2048 blocks
    catproj_kernel<<<grid, RPB, 0, stream>>>(reward, probs, not_done, out);
}

// Round 5
// 197.631 us; speedup vs baseline: 2.1642x; 1.0035x over previous
//
#include <hip/hip_runtime.h>

// C51 categorical projection. BS = 524288 rows x 51 atoms, fp32.
// Round 5: single-wave workgroups. R4 showed no pipe >27% busy -- the
// bottleneck is barrier-phase serialization (stage -> vmcnt(0)+s_barrier ->
// compute -> s_barrier -> writeout, only 3 blocks/CU). The tile transpose
// only communicates WITHIN a wave, so RPB=64 + __launch_bounds__(64) lets
// the compiler elide s_barrier entirely (blocksize <= wavesize): 12
// independent wave-pipelines per CU (LDS-capped at 13056 B/block), each
// hiding its own load latency against its neighbors.
//
// History: R1 stage+RMW scatter 71us; R2 ds_add_f32 atomics 298us (never
// again); R3 direct global row reads 184us (204B-stride fragmentation,
// FETCH 3x); R4 stage+merge-scatter 77us (conflicts 8.1M->1.1M, no dur
// change -> serialization-bound).
//
// Merge-scatter: b(a) = clamp(base2 + c*a, 0, 50), slope c <= 0.99 < 1 ->
// floor(b) advances 0 or 1 per atom -> each bin written exactly once,
// float-only tracking (curf compare, pointer-increment dst).

#define NUM_ATOMS 51
#define RPB 64
#define TILE (RPB * NUM_ATOMS)      // 3264 floats = 13056 B -> 12 blocks/CU
#define NV4 (TILE / 4)              // 816 float4 = 12*64 + 48

__global__ __launch_bounds__(RPB, 3) void catproj_kernel(
    const float* __restrict__ reward,
    const float* __restrict__ probs,
    const float* __restrict__ not_done,
    float* __restrict__ out)
{
    __shared__ float lds[TILE];

    const int tid = threadIdx.x;               // 0..63 = lane
    const int row = blockIdx.x * RPB + tid;
    const int base = blockIdx.x * TILE;

    const float r  = reward[row];
    const float nd = not_done[row];

    // ---- Stage probs tile into LDS: flat coalesced b128 copy ----
    const float4* __restrict__ p4 = (const float4*)(probs + base);
    float4* __restrict__ l4 = (float4*)lds;
#pragma unroll
    for (int k = 0; k < 12; ++k) {
        const int i4 = k * RPB + tid;
        l4[i4] = p4[i4];
    }
    if (tid < NV4 - 12 * RPB)                  // remainder: 48 float4s
        l4[12 * RPB + tid] = p4[12 * RPB + tid];
    __syncthreads();                           // single wave: barrier elided,
                                               // just the waitcnt we need

    // ---- Read own contiguous row into registers (ds_read2 pairs) ----
    float* __restrict__ myrow = lds + tid * NUM_ATOMS;
    float p[NUM_ATOMS];
#pragma unroll
    for (int a = 0; a < NUM_ATOMS; ++a) p[a] = myrow[a];

    // Own row only from here (intra-wave, no sync needed).
#pragma unroll
    for (int a = 0; a < NUM_ATOMS; ++a) myrow[a] = 0.0f;

    // ---- Merge-scatter: one write per output bin, float-only tracking ----
    const float c     = 0.99f * nd;
    const float base2 = fmaf(-25.f, c, fmaf(2.5f, r, 25.f)); // 2.5r+25-25c
    float curf = floorf(fminf(fmaxf(base2, 0.f), 50.f));     // lf(a=0)
    float* dst = myrow + (int)curf;
    float accL = 0.f, accU = 0.f;
#pragma unroll
    for (int a = 0; a < NUM_ATOMS; ++a) {
        float b = fmaf(c, (float)a, base2);
        b = fminf(fmaxf(b, 0.f), 50.f);
        const float lf = floorf(b);
        const float pa = p[a];
        const float mu = (b - lf) * pa;   // upper mass (0 when b integral)
        const float ml = pa - mu;         // lower mass
        if (lf != curf) {                 // advances by exactly 1 (slope < 1)
            *dst = accL;                  // bin complete: single ds_write_b32
            ++dst;
            accL = accU;
            accU = 0.f;
            curf = lf;
        }
        accL += ml;
        accU += mu;
    }
    *dst = accL;
    if (curf < 50.f) dst[1] = accU;       // accU == 0 when curf == 50
    __syncthreads();                      // elided; waitcnt ordering only

    // ---- Flat coalesced writeout ----
    const float4* __restrict__ s4 = (const float4*)lds;
    float4* __restrict__ o4 = (float4*)(out + base);
#pragma unroll
    for (int k = 0; k < 12; ++k) {
        const int i4 = k * RPB + tid;
        o4[i4] = s4[i4];
    }
    if (tid < NV4 - 12 * RPB)
        o4[12 * RPB + tid] = s4[12 * RPB + tid];
}

extern "C" void kernel_launch(void* const* d_in, const int* in_sizes, int n_in,
                              void* d_out, int out_size, void* d_ws, size_t ws_size,
                              hipStream_t stream) {
    const float* reward   = (const float*)d_in[0];
    const float* probs    = (const float*)d_in[1];
    const float* not_done = (const float*)d_in[2];
    float* out = (float*)d_out;

    const int bs = in_sizes[0];              // 524288
    const int grid = bs / RPB;               // 8192 blocks
    catproj_kernel<<<grid, RPB, 0, stream>>>(reward, probs, not_done, out);
}